// Round 7
// baseline (48.432 us; speedup 1.0000x reference)
//
#include <hip/hip_runtime.h>
#include <cstdint>

typedef __bf16 bf16x8 __attribute__((ext_vector_type(8)));
typedef float f32x4 __attribute__((ext_vector_type(4)));
typedef unsigned short u16;

#define NROWS 4096
#define DIM 512
#define ZROWS 8192
#define DIMP 128     /* projected dims (Walsh coefficients 0..127) */
#define BM 128
#define BK 32
#define NTILES 64    /* 8192/128 */
#define NBLOCKS 2080 /* 64*65/2 upper-triangular tile pairs */
#define GRID 768     /* 3 blocks/CU x 256 CU — fully resident, persistent */
#define THR 80.0f    /* certify-skip: d_proj>=80 => d_true>=~79 => sum < 1e-9 */

#define AS1 __attribute__((address_space(1)))
#define AS3 __attribute__((address_space(3)))

// ---------------- kernel 1: row norms (f32) + 128-dim Walsh projection -----------
// FWHT over 512 elems: lane l holds contiguous elems [8l,8l+8). 3 in-lane stages +
// 6 shfl_xor stages = exact Sylvester-order WHT. Rows of Hadamard/sqrt(512) are
// exactly orthonormal => for the 128-subset: d_proj <= d_true (Parseval).
__global__ __launch_bounds__(256) void prep_kernel(const float* __restrict__ lbl,
                                                   const float* __restrict__ pred,
                                                   u16* __restrict__ Q,
                                                   float* __restrict__ xnorm,
                                                   float* __restrict__ pnorm) {
    const int w = threadIdx.x >> 6;
    const int l = threadIdx.x & 63;
    const int row = blockIdx.x * 4 + w;
    const float* src = (row < NROWS) ? (lbl + (size_t)row * DIM)
                                     : (pred + (size_t)(row - NROWS) * DIM);
    const float4 v0 = *(const float4*)(src + l * 8);
    const float4 v1 = *(const float4*)(src + l * 8 + 4);
    float h[8] = {v0.x, v0.y, v0.z, v0.w, v1.x, v1.y, v1.z, v1.w};

    float nrm = 0.f;  // exact f32 norm of the ORIGINAL row (for the exact fallback)
#pragma unroll
    for (int j = 0; j < 8; ++j) nrm += h[j] * h[j];
#pragma unroll
    for (int off = 32; off; off >>= 1) nrm += __shfl_xor(nrm, off);
    if (l == 0) xnorm[row] = nrm;

    // FWHT, in-lane stages (len 1,2,4)
#define BFLY(a, b) { float t = h[a]; h[a] = t + h[b]; h[b] = t - h[b]; }
    BFLY(0, 1) BFLY(2, 3) BFLY(4, 5) BFLY(6, 7)
    BFLY(0, 2) BFLY(1, 3) BFLY(4, 6) BFLY(5, 7)
    BFLY(0, 4) BFLY(1, 5) BFLY(2, 6) BFLY(3, 7)
#undef BFLY
    // cross-lane stages (len 8..256): position 8l+j pairs with 8(l^m)+j
#pragma unroll
    for (int m = 1; m <= 32; m <<= 1) {
#pragma unroll
        for (int j = 0; j < 8; ++j) {
            float p = __shfl_xor(h[j], m);
            h[j] = (l & m) ? (p - h[j]) : (h[j] + p);
        }
    }
    // quantize q = h / sqrt(512) to bf16 (RNE); pnorm from the bf16-rounded values
    float s = 0.f;
    uint32_t pk[4];
#pragma unroll
    for (int jj = 0; jj < 4; ++jj) {
        uint32_t b0 = __float_as_uint(h[2 * jj] * 0.04419417382f);
        uint32_t b1 = __float_as_uint(h[2 * jj + 1] * 0.04419417382f);
        uint32_t r0 = (b0 + 0x7fffu + ((b0 >> 16) & 1u)) >> 16;
        uint32_t r1 = (b1 + 0x7fffu + ((b1 >> 16) & 1u)) >> 16;
        pk[jj] = r0 | (r1 << 16);
        float fb0 = __uint_as_float(r0 << 16);
        float fb1 = __uint_as_float(r1 << 16);
        s += fb0 * fb0 + fb1 * fb1;
    }
    if (l < 16) *(uint4*)(Q + (size_t)row * DIMP + l * 8) = make_uint4(pk[0], pk[1], pk[2], pk[3]);
    s = (l < 16) ? s : 0.f;
#pragma unroll
    for (int off = 32; off; off >>= 1) s += __shfl_xor(s, off);
    if (l == 0) pnorm[row] = s;
}

// ---------------- kernel 2: persistent pipelined K=128 filter GEMM ---------------
// 768 blocks (3/CU, all resident). Each block streams 2-3 tile-pairs as a chunk
// stream (4 chunks/tile, BK=32) through 3 LDS buffers, lookahead-2 prefetch:
//   phase c: vmcnt(4) gate -> s_barrier -> ds_read(buf c%3) -> STAGE(c+2) ->
//            setprio(1) 16xMFMA setprio(0) -> [tile epilogue if c&3==3]
// Safety: chunk arrival = per-wave vmcnt gate before barrier; buffer recycle =
// STAGE(c+2) targets the buffer last read in phase c-1, whose reads all waves
// consumed (register deps) before passing phase c's barrier. vmcnt never drains
// to 0 in steady state (T4). B staged unconditionally (uniform 4 loads/thread).
__global__ __launch_bounds__(256, 3) void mmd_filter_kernel(const u16* __restrict__ Q,
                                                            const float* __restrict__ pnorm,
                                                            const float* __restrict__ lbl,
                                                            const float* __restrict__ pred,
                                                            const float* __restrict__ xnorm,
                                                            float* __restrict__ partials) {
    __shared__ u16 lds[3][2][BM * BK];  // [buf][A/B][128*32] = 48 KiB
    __shared__ float red[4];

    const int bid = (int)blockIdx.x;
    const int tid = threadIdx.x;
    const int w = tid >> 6;
    const int l = tid & 63;
    const int warpM = w >> 1, warpN = w & 1;
    const char* qbytes = (const char*)Q;

    // ---- decode tile list (2 or 3 tiles, stride GRID over the triangle) ----
    int bmc = 0, rem = bid;
    while (rem >= NTILES - bmc) { rem -= NTILES - bmc; ++bmc; }
    const int bm0 = bmc, bn0 = bmc + rem;
    int bm1 = 0, bn1 = 0, bm2 = 0, bn2 = 0, nT = 1;
    rem += GRID;
    while (bmc < NTILES && rem >= NTILES - bmc) { rem -= NTILES - bmc; ++bmc; }
    if (bmc < NTILES) {
        bm1 = bmc; bn1 = bmc + rem; nT = 2;
        rem += GRID;
        while (bmc < NTILES && rem >= NTILES - bmc) { rem -= NTILES - bmc; ++bmc; }
        if (bmc < NTILES) { bm2 = bmc; bn2 = bmc + rem; nT = 3; }
    }
    const int NC = 4 * nT;

    // ---- staging: chunk c -> lds[c%3]; pre-swizzled source slot (rule #21) ----
    const int srow = w * 16 + (l >> 2);                        // + it*64
    const int csrc = ((l & 3) << 4) ^ (((l >> 2) & 3) << 4);   // slot ^ ((row&3)<<4)
    auto STAGE = [&](int c) {
        const int ti = c >> 2, kt = c & 3, b = c % 3;
        const int bmT = (ti == 0) ? bm0 : ((ti == 1) ? bm1 : bm2);
        const int bnT = (ti == 0) ? bn0 : ((ti == 1) ? bn1 : bn2);
        const char* gA = qbytes + (size_t)bmT * BM * (DIMP * 2) + kt * 64 + csrc;
        const char* gB = qbytes + (size_t)bnT * BM * (DIMP * 2) + kt * 64 + csrc;
        char* lA = (char*)&lds[b][0][0] + w * 1024 + l * 16;
        char* lB = (char*)&lds[b][1][0] + w * 1024 + l * 16;
#pragma unroll
        for (int it = 0; it < 2; ++it) {
            const size_t roff = (size_t)(it * 64 + srow) * (DIMP * 2);
            __builtin_amdgcn_global_load_lds((const AS1 void*)(gA + roff),
                                             (AS3 void*)(lA + it * 4096), 16, 0, 0);
            __builtin_amdgcn_global_load_lds((const AS1 void*)(gB + roff),
                                             (AS3 void*)(lB + it * 4096), 16, 0, 0);
        }
    };

    const int klane = ((l >> 4) * 16) ^ ((l & 3) << 4);  // read-side swizzle
    f32x4 acc[4][4];
#pragma unroll
    for (int m = 0; m < 4; ++m)
#pragma unroll
        for (int n = 0; n < 4; ++n) acc[m][n] = (f32x4){0.f, 0.f, 0.f, 0.f};
    float grand = 0.f;

    STAGE(0); STAGE(1);  // lookahead-2 prologue (8 loads in flight)

    for (int c = 0; c < NC; ++c) {
        if (c + 1 < NC) asm volatile("s_waitcnt vmcnt(4)" ::: "memory");
        else            asm volatile("s_waitcnt vmcnt(0)" ::: "memory");
        __builtin_amdgcn_s_barrier();

        const int b = c % 3;
        const char* abase = (const char*)&lds[b][0][0];
        const char* bbase = (const char*)&lds[b][1][0];
        bf16x8 af[4], bg[4];
#pragma unroll
        for (int m = 0; m < 4; ++m) {
            const int rr = warpM * 64 + m * 16 + (l & 15);
            af[m] = *(const bf16x8*)(abase + rr * 64 + klane);
        }
#pragma unroll
        for (int n = 0; n < 4; ++n) {
            const int rr = warpN * 64 + n * 16 + (l & 15);
            bg[n] = *(const bf16x8*)(bbase + rr * 64 + klane);
        }
        if (c + 2 < NC) STAGE(c + 2);

        __builtin_amdgcn_s_setprio(1);
#pragma unroll
        for (int m = 0; m < 4; ++m)
#pragma unroll
            for (int n = 0; n < 4; ++n)
                acc[m][n] = __builtin_amdgcn_mfma_f32_16x16x32_bf16(af[m], bg[n], acc[m][n], 0, 0, 0);
        __builtin_amdgcn_s_setprio(0);

        if ((c & 3) == 3) {  // ---- tile epilogue (register-only; no barrier) ----
            const int ti = c >> 2;
            const int bmT = (ti == 0) ? bm0 : ((ti == 1) ? bm1 : bm2);
            const int bnT = (ti == 0) ? bn0 : ((ti == 1) ? bn1 : bn2);
            const int baseI = bmT * BM + warpM * 64;
            const int baseJ = bnT * BM + warpN * 64;
            float pj[4];
#pragma unroll
            for (int n = 0; n < 4; ++n) pj[n] = pnorm[baseJ + n * 16 + (l & 15)];
            float local = 0.f;
#pragma unroll
            for (int m = 0; m < 4; ++m) {
                const float4 pi = *(const float4*)(pnorm + baseI + m * 16 + (l >> 4) * 4);
#pragma unroll
                for (int n = 0; n < 4; ++n) {
                    float d[4];
                    d[0] = (pi.x + pj[n]) - 2.f * acc[m][n][0];
                    d[1] = (pi.y + pj[n]) - 2.f * acc[m][n][1];
                    d[2] = (pi.z + pj[n]) - 2.f * acc[m][n][2];
                    d[3] = (pi.w + pj[n]) - 2.f * acc[m][n][3];
                    const int i0 = baseI + m * 16 + (l >> 4) * 4;
                    const int j = baseJ + n * 16 + (l & 15);
#pragma unroll
                    for (int r = 0; r < 4; ++r) {
                        // i==j is exp(0)=1 exactly — constant in the final reduce
                        unsigned long long bal = __ballot((d[r] < THR) && (i0 + r != j));
                        while (bal) {  // ≈never; wave-cooperative exact f32 term
                            const int src = __ffsll((long long)bal) - 1;
                            bal &= bal - 1;
                            const int ii = __shfl(i0 + r, src);
                            const int jj = __shfl(j, src);
                            const float* ri = (ii < NROWS) ? lbl + (size_t)ii * DIM
                                                           : pred + (size_t)(ii - NROWS) * DIM;
                            const float* rj = (jj < NROWS) ? lbl + (size_t)jj * DIM
                                                           : pred + (size_t)(jj - NROWS) * DIM;
                            const float4 a0 = *(const float4*)(ri + l * 8);
                            const float4 a1 = *(const float4*)(ri + l * 8 + 4);
                            const float4 c0 = *(const float4*)(rj + l * 8);
                            const float4 c1 = *(const float4*)(rj + l * 8 + 4);
                            float p = a0.x * c0.x + a0.y * c0.y + a0.z * c0.z + a0.w * c0.w +
                                      a1.x * c1.x + a1.y * c1.y + a1.z * c1.z + a1.w * c1.w;
#pragma unroll
                            for (int off = 32; off; off >>= 1) p += __shfl_xor(p, off);
                            if (l == src) {
                                float dt = xnorm[ii] + xnorm[jj] - 2.f * p;
                                local += exp2f(-0.72134752f * dt);
                            }
                        }
                    }
                }
            }
            const float sgn = ((bmT < 32) == (bnT < 32)) ? 1.f : -1.f;
            grand += local * sgn * ((bmT == bnT) ? 1.f : 2.f);
#pragma unroll
            for (int m = 0; m < 4; ++m)
#pragma unroll
                for (int n = 0; n < 4; ++n) acc[m][n] = (f32x4){0.f, 0.f, 0.f, 0.f};
        }
    }

    // ---- one cross-wave reduce per block ----
#pragma unroll
    for (int off = 32; off; off >>= 1) grand += __shfl_xor(grand, off);
    if (l == 0) red[w] = grand;
    __syncthreads();
    if (tid == 0) partials[bid] = red[0] + red[1] + red[2] + red[3];
}

// ---------------- kernel 3: deterministic final reduce ---------------------------
__global__ __launch_bounds__(256) void reduce_kernel(const float* __restrict__ partials,
                                                     float* __restrict__ out, int n) {
    __shared__ float red[4];
    float s = 0.f;
    for (int i = threadIdx.x; i < n; i += 256) s += partials[i];
#pragma unroll
    for (int off = 32; off; off >>= 1) s += __shfl_xor(s, off);
    if ((threadIdx.x & 63) == 0) red[threadIdx.x >> 6] = s;
    __syncthreads();
    if (threadIdx.x == 0)  // + 8192 = the Z-diagonal (exp(0)=1, sign +1, exact)
        out[0] = (red[0] + red[1] + red[2] + red[3] + 8192.f) * (1.f / 16777216.f);
}

extern "C" void kernel_launch(void* const* d_in, const int* in_sizes, int n_in,
                              void* d_out, int out_size, void* d_ws, size_t ws_size,
                              hipStream_t stream) {
    const float* lbl = (const float*)d_in[0];
    const float* pred = (const float*)d_in[1];
    u16* Q = (u16*)d_ws;                                              // 2 MiB
    float* xnorm = (float*)((char*)d_ws + (size_t)ZROWS * DIMP * 2);  // 32 KiB
    float* pnorm = xnorm + ZROWS;                                     // 32 KiB
    float* partials = pnorm + ZROWS;                                  // 3 KiB

    prep_kernel<<<ZROWS / 4, 256, 0, stream>>>(lbl, pred, Q, xnorm, pnorm);
    mmd_filter_kernel<<<GRID, 256, 0, stream>>>(Q, pnorm, lbl, pred, xnorm, partials);
    reduce_kernel<<<1, 256, 0, stream>>>(partials, (float*)d_out, GRID);
}